// Round 1
// baseline (1085.091 us; speedup 1.0000x reference)
//
#include <hip/hip_runtime.h>
#include <math.h>

#define CIN   3
#define DIN   16
#define HWIN  64
#define COUT  24
#define DOUT  14
#define HOUT  62
#define WOUT  62

#define TILE_H    4
#define NTILES    16                     // ceil(62/4)
#define NTHR      384                    // 6 waves: wave q handles co = q*4 .. q*4+3
#define ROWS_IN   (TILE_H + 2)           // 6 input rows per tile
#define RP        68                     // padded row length (floats): 16B-aligned rows, even bank spread
#define PLANE_F   (CIN * ROWS_IN * RP)   // 1224 floats per depth-plane slot
#define SM_RP     66
#define SM_STRIDE (TILE_H * SM_RP)       // 264
#define SM_SIZE   (COUT * SM_STRIDE)     // 6336 floats = 25344 B (>= 3*PLANE_F = 3672 -> overlay ok)

// x:    [128][3][16][64][64] fp32
// w:    [24][3][3][3][3]     fp32 (co, cin, kd, kh, kw)
// out:  [128][24][62][62]    softmax over co of (min over dz of conv+bias)
//
// Block = (b, 4-row tile). Wave q: co = 4q..4q+3 (wave-uniform -> weights via s_load, SMEM pipe).
// Lane: r = lane>>4 (row), wg = lane&15 (wo = 4*wg..4*wg+3). Each LDS row read feeds
// 4co x 3kw x 4px = 48 FMAs. Rolling 3-plane LDS window, reg-prefetched staging.

__global__ __launch_bounds__(NTHR, 8) void conv_min_softmax_v3(
    const float* __restrict__ x,
    const float* __restrict__ w,
    const float* __restrict__ bias,
    float* __restrict__ out)
{
    __shared__ __align__(16) float smem[SM_SIZE];   // sx (3 planes) overlaid later by sm

    const int tid  = threadIdx.x;
    const int bid  = blockIdx.x;
    const int rt   = bid & (NTILES - 1);
    const int b    = bid >> 4;

    const int q    = __builtin_amdgcn_readfirstlane(tid >> 6);   // wave id 0..5 (uniform)
    const int lane = tid & 63;
    const int r    = lane >> 4;          // 0..3 output row within tile
    const int wg   = lane & 15;          // 0..15 -> wo = wg*4 .. wg*4+3

    const float* __restrict__ wq = w + q * (4 * 81);             // uniform -> s_load
    const float bia0 = bias[q * 4 + 0], bia1 = bias[q * 4 + 1],
                bia2 = bias[q * 4 + 2], bia3 = bias[q * 4 + 3];

    // staging: wave q stages input row (rt*4 + q) of each (cin, plane); lane = column
    const int grow = min(rt * TILE_H + q, HWIN - 1);             // clamp for last tile
    const float* __restrict__ xb =
        x + (size_t)b * (CIN * DIN * HWIN * HWIN) + grow * HWIN + lane;

    const int vbase = r * RP + wg * 4;   // lane's offset inside a (cin,kh) pane

    // ---- preload planes 0,1 into slots 0,1; plane 2 left pending in regs ----
    {
        float p0[CIN], p1[CIN];
        #pragma unroll
        for (int c = 0; c < CIN; ++c) p0[c] = xb[(c * DIN + 0) * (HWIN * HWIN)];
        #pragma unroll
        for (int c = 0; c < CIN; ++c) p1[c] = xb[(c * DIN + 1) * (HWIN * HWIN)];
        #pragma unroll
        for (int c = 0; c < CIN; ++c) smem[0 * PLANE_F + (c * ROWS_IN + q) * RP + lane] = p0[c];
        #pragma unroll
        for (int c = 0; c < CIN; ++c) smem[1 * PLANE_F + (c * ROWS_IN + q) * RP + lane] = p1[c];
    }
    float pf[CIN];
    #pragma unroll
    for (int c = 0; c < CIN; ++c) pf[c] = xb[(c * DIN + 2) * (HWIN * HWIN)];

    float m[4][4];
    #pragma unroll
    for (int cop = 0; cop < 4; ++cop)
        #pragma unroll
        for (int i = 0; i < 4; ++i) m[cop][i] = 1e30f;

    int o0 = 0, o1 = PLANE_F, o2 = 2 * PLANE_F;   // rolling slot base offsets (uniform)

    #pragma unroll 1
    for (int dz = 0; dz < DOUT; ++dz) {
        __syncthreads();                                  // prior readers of slot o2 done
        #pragma unroll
        for (int c = 0; c < CIN; ++c)
            smem[o2 + (c * ROWS_IN + q) * RP + lane] = pf[c];     // plane dz+2
        const int dnext = (dz + 3 < DIN) ? (dz + 3) : (DIN - 1);
        #pragma unroll
        for (int c = 0; c < CIN; ++c)                              // prefetch plane dz+3
            pf[c] = xb[(c * DIN + dnext) * (HWIN * HWIN)];         // latency hides under compute
        __syncthreads();                                  // staging visible

        float acc[4][4];
        #pragma unroll
        for (int cop = 0; cop < 4; ++cop)
            #pragma unroll
            for (int i = 0; i < 4; ++i) acc[cop][i] = 0.f;

        #pragma unroll
        for (int kd = 0; kd < 3; ++kd) {
            const int ob = (kd == 0) ? o0 : (kd == 1) ? o1 : o2;
            #pragma unroll
            for (int cin = 0; cin < CIN; ++cin) {
                #pragma unroll
                for (int kh = 0; kh < 3; ++kh) {
                    const float* rp = &smem[ob + (cin * ROWS_IN + kh) * RP + vbase];
                    const float4 a4 = *(const float4*)rp;          // ds_read_b128, even banks
                    const float2 a2 = *(const float2*)(rp + 4);    // ds_read_b64
                    const float xr[6] = { a4.x, a4.y, a4.z, a4.w, a2.x, a2.y };
                    #pragma unroll
                    for (int cop = 0; cop < 4; ++cop) {
                        const float* wk = wq + cop * 81 + cin * 27 + kd * 9 + kh * 3;
                        #pragma unroll
                        for (int kw = 0; kw < 3; ++kw) {
                            const float wv = wk[kw];               // scalar (SMEM) load
                            #pragma unroll
                            for (int i = 0; i < 4; ++i)
                                acc[cop][i] = fmaf(wv, xr[i + kw], acc[cop][i]);
                        }
                    }
                }
            }
        }

        #pragma unroll
        for (int cop = 0; cop < 4; ++cop)
            #pragma unroll
            for (int i = 0; i < 4; ++i)
                m[cop][i] = fminf(m[cop][i], acc[cop][i]);

        const int tmp = o0; o0 = o1; o1 = o2; o2 = tmp;   // rotate plane slots
    }

    __syncthreads();      // sx dead; reuse smem as the 24-channel min matrix

    #pragma unroll
    for (int i = 0; i < 4; ++i) {
        const int p = r * SM_RP + wg * 4 + i;
        smem[(q * 4 + 0) * SM_STRIDE + p] = m[0][i] + bia0;
        smem[(q * 4 + 1) * SM_STRIDE + p] = m[1][i] + bia1;
        smem[(q * 4 + 2) * SM_STRIDE + p] = m[2][i] + bia2;
        smem[(q * 4 + 3) * SM_STRIDE + p] = m[3][i] + bia3;
    }
    __syncthreads();

    if (tid < 256) {                      // 4 rows x 64 cols, one pixel per thread
        const int row = tid >> 6;
        const int col = tid & 63;
        const int ho  = rt * TILE_H + row;
        if (col < WOUT && ho < HOUT) {
            float v[COUT];
            float mx = -1e30f;
            #pragma unroll
            for (int c = 0; c < COUT; ++c) {
                v[c] = smem[c * SM_STRIDE + row * SM_RP + col];
                mx = fmaxf(mx, v[c]);
            }
            float s = 0.f;
            #pragma unroll
            for (int c = 0; c < COUT; ++c) { v[c] = __expf(v[c] - mx); s += v[c]; }
            const float inv = 1.f / s;
            float* ob = out + (size_t)b * COUT * (HOUT * WOUT) + ho * WOUT + col;
            #pragma unroll
            for (int c = 0; c < COUT; ++c)
                ob[(size_t)c * (HOUT * WOUT)] = v[c] * inv;
        }
    }
}

extern "C" void kernel_launch(void* const* d_in, const int* in_sizes, int n_in,
                              void* d_out, int out_size, void* d_ws, size_t ws_size,
                              hipStream_t stream) {
    const float* x    = (const float*)d_in[0];
    const float* w    = (const float*)d_in[1];
    const float* bias = (const float*)d_in[2];
    float* out = (float*)d_out;

    conv_min_softmax_v3<<<128 * NTILES, NTHR, 0, stream>>>(x, w, bias, out);
}

// Round 2
// 1023.929 us; speedup vs baseline: 1.0597x; 1.0597x over previous
//
#include <hip/hip_runtime.h>
#include <math.h>

#define CIN   3
#define DIN   16
#define HWIN  64
#define COUT  24
#define DOUT  14
#define HOUT  62
#define WOUT  62

#define TILE_H    4
#define NTILES    16                     // ceil(62/4)
#define NTHR      384                    // 6 waves: wave q handles co = q*4 .. q*4+3
#define ROWS_IN   (TILE_H + 2)           // 6 input rows per tile
#define RP        68                     // padded row length (floats): 16B-aligned rows, even bank spread
#define PLANE_F   (CIN * ROWS_IN * RP)   // 1224 floats per depth-plane slot
#define SM_RP     66
#define SM_STRIDE (TILE_H * SM_RP)       // 264
#define SM_SIZE   (COUT * SM_STRIDE)     // 6336 floats = 25344 B (>= 3*PLANE_F = 3672 -> overlay ok)

// x:    [128][3][16][64][64] fp32
// w:    [24][3][3][3][3]     fp32 (co, cin, kd, kh, kw)
// out:  [128][24][62][62]    softmax over co of (min over dz of conv+bias)
//
// Block = (b, 4-row tile). Wave q: co = 4q..4q+3 (wave-uniform -> weights via s_load, SMEM pipe).
// Lane: r = lane>>4 (row), wg = lane&15 (wo = 4*wg..4*wg+3). Each LDS row read feeds
// 4co x 3kw x 4px = 48 FMAs -> 0.5 B/FMA, below the 0.66 B/FMA LDS-BW roofline.
//
// v4 = v3 with __launch_bounds__(384,4) instead of (384,8). The (,8) bound capped
// VGPRs at 64 (allocator picked 32 arch VGPRs) and forced acc/m through AGPR
// copies -> ~3 VALU instrs per FMA -> 1080us. (,4) allows 128 VGPRs so the
// ~60 live per-lane values stay in arch VGPRs.

__global__ __launch_bounds__(NTHR, 4) void conv_min_softmax_v4(
    const float* __restrict__ x,
    const float* __restrict__ w,
    const float* __restrict__ bias,
    float* __restrict__ out)
{
    __shared__ __align__(16) float smem[SM_SIZE];   // sx (3 planes) overlaid later by sm

    const int tid  = threadIdx.x;
    const int bid  = blockIdx.x;
    const int rt   = bid & (NTILES - 1);
    const int b    = bid >> 4;

    const int q    = __builtin_amdgcn_readfirstlane(tid >> 6);   // wave id 0..5 (uniform)
    const int lane = tid & 63;
    const int r    = lane >> 4;          // 0..3 output row within tile
    const int wg   = lane & 15;          // 0..15 -> wo = wg*4 .. wg*4+3

    const float* __restrict__ wq = w + q * (4 * 81);             // uniform -> s_load
    const float bia0 = bias[q * 4 + 0], bia1 = bias[q * 4 + 1],
                bia2 = bias[q * 4 + 2], bia3 = bias[q * 4 + 3];

    // staging: wave q stages input row (rt*4 + q) of each (cin, plane); lane = column
    const int grow = min(rt * TILE_H + q, HWIN - 1);             // clamp for last tile
    const float* __restrict__ xb =
        x + (size_t)b * (CIN * DIN * HWIN * HWIN) + grow * HWIN + lane;

    const int vbase = r * RP + wg * 4;   // lane's offset inside a (cin,kh) pane

    // ---- preload planes 0,1 into slots 0,1; plane 2 left pending in regs ----
    {
        float p0[CIN], p1[CIN];
        #pragma unroll
        for (int c = 0; c < CIN; ++c) p0[c] = xb[(c * DIN + 0) * (HWIN * HWIN)];
        #pragma unroll
        for (int c = 0; c < CIN; ++c) p1[c] = xb[(c * DIN + 1) * (HWIN * HWIN)];
        #pragma unroll
        for (int c = 0; c < CIN; ++c) smem[0 * PLANE_F + (c * ROWS_IN + q) * RP + lane] = p0[c];
        #pragma unroll
        for (int c = 0; c < CIN; ++c) smem[1 * PLANE_F + (c * ROWS_IN + q) * RP + lane] = p1[c];
    }
    float pf[CIN];
    #pragma unroll
    for (int c = 0; c < CIN; ++c) pf[c] = xb[(c * DIN + 2) * (HWIN * HWIN)];

    float m[4][4];
    #pragma unroll
    for (int cop = 0; cop < 4; ++cop)
        #pragma unroll
        for (int i = 0; i < 4; ++i) m[cop][i] = 1e30f;

    int o0 = 0, o1 = PLANE_F, o2 = 2 * PLANE_F;   // rolling slot base offsets (uniform)

    #pragma unroll 1
    for (int dz = 0; dz < DOUT; ++dz) {
        __syncthreads();                                  // prior readers of slot o2 done
        #pragma unroll
        for (int c = 0; c < CIN; ++c)
            smem[o2 + (c * ROWS_IN + q) * RP + lane] = pf[c];     // plane dz+2
        const int dnext = (dz + 3 < DIN) ? (dz + 3) : (DIN - 1);
        #pragma unroll
        for (int c = 0; c < CIN; ++c)                              // prefetch plane dz+3
            pf[c] = xb[(c * DIN + dnext) * (HWIN * HWIN)];         // latency hides under compute
        __syncthreads();                                  // staging visible

        float acc[4][4];
        #pragma unroll
        for (int cop = 0; cop < 4; ++cop)
            #pragma unroll
            for (int i = 0; i < 4; ++i) acc[cop][i] = 0.f;

        #pragma unroll
        for (int kd = 0; kd < 3; ++kd) {
            const int ob = (kd == 0) ? o0 : (kd == 1) ? o1 : o2;
            #pragma unroll
            for (int cin = 0; cin < CIN; ++cin) {
                #pragma unroll
                for (int kh = 0; kh < 3; ++kh) {
                    const float* rp = &smem[ob + (cin * ROWS_IN + kh) * RP + vbase];
                    const float4 a4 = *(const float4*)rp;          // ds_read_b128
                    const float2 a2 = *(const float2*)(rp + 4);    // ds_read_b64
                    const float xr[6] = { a4.x, a4.y, a4.z, a4.w, a2.x, a2.y };
                    #pragma unroll
                    for (int cop = 0; cop < 4; ++cop) {
                        const float* wk = wq + cop * 81 + cin * 27 + kd * 9 + kh * 3;
                        #pragma unroll
                        for (int kw = 0; kw < 3; ++kw) {
                            const float wv = wk[kw];               // scalar (SMEM) load
                            #pragma unroll
                            for (int i = 0; i < 4; ++i)
                                acc[cop][i] = fmaf(wv, xr[i + kw], acc[cop][i]);
                        }
                    }
                }
            }
        }

        #pragma unroll
        for (int cop = 0; cop < 4; ++cop)
            #pragma unroll
            for (int i = 0; i < 4; ++i)
                m[cop][i] = fminf(m[cop][i], acc[cop][i]);

        const int tmp = o0; o0 = o1; o1 = o2; o2 = tmp;   // rotate plane slots
    }

    __syncthreads();      // sx dead; reuse smem as the 24-channel min matrix

    #pragma unroll
    for (int i = 0; i < 4; ++i) {
        const int p = r * SM_RP + wg * 4 + i;
        smem[(q * 4 + 0) * SM_STRIDE + p] = m[0][i] + bia0;
        smem[(q * 4 + 1) * SM_STRIDE + p] = m[1][i] + bia1;
        smem[(q * 4 + 2) * SM_STRIDE + p] = m[2][i] + bia2;
        smem[(q * 4 + 3) * SM_STRIDE + p] = m[3][i] + bia3;
    }
    __syncthreads();

    if (tid < 256) {                      // 4 rows x 64 cols, one pixel per thread
        const int row = tid >> 6;
        const int col = tid & 63;
        const int ho  = rt * TILE_H + row;
        if (col < WOUT && ho < HOUT) {
            float v[COUT];
            float mx = -1e30f;
            #pragma unroll
            for (int c = 0; c < COUT; ++c) {
                v[c] = smem[c * SM_STRIDE + row * SM_RP + col];
                mx = fmaxf(mx, v[c]);
            }
            float s = 0.f;
            #pragma unroll
            for (int c = 0; c < COUT; ++c) { v[c] = __expf(v[c] - mx); s += v[c]; }
            const float inv = 1.f / s;
            float* ob = out + (size_t)b * COUT * (HOUT * WOUT) + ho * WOUT + col;
            #pragma unroll
            for (int c = 0; c < COUT; ++c)
                ob[(size_t)c * (HOUT * WOUT)] = v[c] * inv;
        }
    }
}

extern "C" void kernel_launch(void* const* d_in, const int* in_sizes, int n_in,
                              void* d_out, int out_size, void* d_ws, size_t ws_size,
                              hipStream_t stream) {
    const float* x    = (const float*)d_in[0];
    const float* w    = (const float*)d_in[1];
    const float* bias = (const float*)d_in[2];
    float* out = (float*)d_out;

    conv_min_softmax_v4<<<128 * NTILES, NTHR, 0, stream>>>(x, w, bias, out);
}

// Round 3
// 601.147 us; speedup vs baseline: 1.8050x; 1.7033x over previous
//
#include <hip/hip_runtime.h>
#include <math.h>

#define CIN   3
#define DIN   16
#define HWIN  64
#define COUT  24
#define DOUT  14
#define HOUT  62
#define WOUT  62

#define TILE_H    4
#define NTILES    16                     // 62 rows -> 16 tiles of 4 (last partially masked)
#define NTHR      384                    // 6 waves; wave q owns co = 4q..4q+3
#define ROWS_IN   6                      // input rows per tile
#define RP        68                     // padded x row (floats)
#define PLANE_F   (CIN * ROWS_IN * RP)   // 1224 floats per depth-plane slot
#define XW_F      (3 * PLANE_F)          // 3672 floats: 3 rolling plane slots
#define WOFF      XW_F                   // weight region base (floats)
#define WPAD_F    (COUT * 27 * 4)        // 2592 floats: [co][g][4], g=kd*9+cin*3+kh
#define SM_RP     64
#define SM_STRIDE (TILE_H * SM_RP)       // 256
#define SM_F      (COUT * SM_STRIDE)     // 6144 floats (overlays x+w region after loop)
#define LDS_F     (XW_F + WPAD_F)        // 6264 floats = 25056 B

// x: [128][3][16][64][64]  w: [24][3][3][3][3]  out: softmax_co(min_dz(conv+bias))
//
// v5 vs v4: (1) weights moved from s_load (SMEM, lgkmcnt-drain serialization,
// SGPR=112) into an LDS repack read via uniform-address ds_read_b128 broadcast
// with immediate offsets; (2) x row (6 floats) read ONCE per (kd,cin,kh) group
// and reused across 4 co -> live state ~55 VGPRs, fits the occupancy-driven
// register cap with no AGPR accumulator shuttling (v3/v4's 3.7 slots/FMA bug).

__global__ __launch_bounds__(NTHR, 2) void conv_min_softmax_v5(
    const float* __restrict__ x,
    const float* __restrict__ w,
    const float* __restrict__ bias,
    float* __restrict__ out)
{
    __shared__ __align__(16) float smem[LDS_F];

    const int tid  = threadIdx.x;
    const int bid  = blockIdx.x;
    const int rt   = bid & (NTILES - 1);
    const int b    = bid >> 4;

    const int q    = __builtin_amdgcn_readfirstlane(tid >> 6);   // wave id (uniform)
    const int lane = tid & 63;
    const int r    = lane >> 4;          // 0..3 output row in tile
    const int wg   = lane & 15;          // 0..15 -> wo = 4*wg .. 4*wg+3
    const int q4   = q * 4;

    // ---- one-time weight repack: w[co][cin][kd][kh][kw] -> smem[WOFF + (co*27+g)*4 + kw]
    for (int i = tid; i < COUT * 81; i += NTHR) {
        const int co   = i / 81;
        const int rem  = i % 81;
        const int cin  = rem / 27;
        const int rem2 = rem % 27;
        const int kd   = rem2 / 9;
        const int kh   = (rem2 % 9) / 3;
        const int kw   = rem2 % 3;
        smem[WOFF + (co * 27 + kd * 9 + cin * 3 + kh) * 4 + kw] = w[i];
    }
    const float bia0 = bias[q4 + 0], bia1 = bias[q4 + 1],
                bia2 = bias[q4 + 2], bia3 = bias[q4 + 3];

    // ---- x staging: wave q stages input row rt*4+q of each (cin, plane); lane = col
    const int grow = min(rt * TILE_H + q, HWIN - 1);
    const float* __restrict__ xb =
        x + (size_t)b * (CIN * DIN * HWIN * HWIN) + grow * HWIN + lane;

    {
        float p0[CIN], p1[CIN];
        #pragma unroll
        for (int c = 0; c < CIN; ++c) p0[c] = xb[(c * DIN + 0) * (HWIN * HWIN)];
        #pragma unroll
        for (int c = 0; c < CIN; ++c) p1[c] = xb[(c * DIN + 1) * (HWIN * HWIN)];
        #pragma unroll
        for (int c = 0; c < CIN; ++c) smem[0 * PLANE_F + (c * ROWS_IN + q) * RP + lane] = p0[c];
        #pragma unroll
        for (int c = 0; c < CIN; ++c) smem[1 * PLANE_F + (c * ROWS_IN + q) * RP + lane] = p1[c];
    }
    float pf[CIN];
    #pragma unroll
    for (int c = 0; c < CIN; ++c) pf[c] = xb[(c * DIN + 2) * (HWIN * HWIN)];

    float m[4][4];
    #pragma unroll
    for (int cop = 0; cop < 4; ++cop)
        #pragma unroll
        for (int i = 0; i < 4; ++i) m[cop][i] = 1e30f;

    const int vbase = r * RP + wg * 4;   // lane offset inside a (cin,kh) pane
    int o0 = 0, o1 = PLANE_F, o2 = 2 * PLANE_F;

    #pragma unroll 1
    for (int dz = 0; dz < DOUT; ++dz) {
        __syncthreads();                                   // prior readers of slot o2 done
        #pragma unroll
        for (int c = 0; c < CIN; ++c)
            smem[o2 + (c * ROWS_IN + q) * RP + lane] = pf[c];      // plane dz+2
        const int dnext = (dz + 3 < DIN) ? (dz + 3) : (DIN - 1);
        #pragma unroll
        for (int c = 0; c < CIN; ++c)                              // prefetch plane dz+3
            pf[c] = xb[(c * DIN + dnext) * (HWIN * HWIN)];
        __syncthreads();                                   // staging (and round-1 weights) visible

        float acc[4][4];
        #pragma unroll
        for (int cop = 0; cop < 4; ++cop)
            #pragma unroll
            for (int i = 0; i < 4; ++i) acc[cop][i] = 0.f;

        #pragma unroll
        for (int kd = 0; kd < 3; ++kd) {
            const int ob = (kd == 0) ? o0 : (kd == 1) ? o1 : o2;
            #pragma unroll
            for (int cin = 0; cin < CIN; ++cin) {
                #pragma unroll
                for (int kh = 0; kh < 3; ++kh) {
                    // x row: read once, reuse for 4 co x 3 kw x 4 px = 48 FMAs
                    const float* rp = &smem[ob + (cin * ROWS_IN + kh) * RP + vbase];
                    const float4 a4 = *(const float4*)rp;          // ds_read_b128
                    const float2 a2 = *(const float2*)(rp + 4);    // ds_read_b64
                    const float xr0 = a4.x, xr1 = a4.y, xr2 = a4.z,
                                xr3 = a4.w, xr4 = a2.x, xr5 = a2.y;
                    const int g = kd * 9 + cin * 3 + kh;
                    #pragma unroll
                    for (int cop = 0; cop < 4; ++cop) {
                        // uniform-address broadcast read, immediate offset
                        const float4 w4 =
                            *(const float4*)&smem[WOFF + ((q4 + cop) * 27 + g) * 4];
                        acc[cop][0] = fmaf(w4.x, xr0, acc[cop][0]);
                        acc[cop][1] = fmaf(w4.x, xr1, acc[cop][1]);
                        acc[cop][2] = fmaf(w4.x, xr2, acc[cop][2]);
                        acc[cop][3] = fmaf(w4.x, xr3, acc[cop][3]);
                        acc[cop][0] = fmaf(w4.y, xr1, acc[cop][0]);
                        acc[cop][1] = fmaf(w4.y, xr2, acc[cop][1]);
                        acc[cop][2] = fmaf(w4.y, xr3, acc[cop][2]);
                        acc[cop][3] = fmaf(w4.y, xr4, acc[cop][3]);
                        acc[cop][0] = fmaf(w4.z, xr2, acc[cop][0]);
                        acc[cop][1] = fmaf(w4.z, xr3, acc[cop][1]);
                        acc[cop][2] = fmaf(w4.z, xr4, acc[cop][2]);
                        acc[cop][3] = fmaf(w4.z, xr5, acc[cop][3]);
                    }
                }
            }
        }

        #pragma unroll
        for (int cop = 0; cop < 4; ++cop)
            #pragma unroll
            for (int i = 0; i < 4; ++i)
                m[cop][i] = fminf(m[cop][i], acc[cop][i]);

        const int tmp = o0; o0 = o1; o1 = o2; o2 = tmp;    // rotate plane slots
    }

    __syncthreads();      // x + weights dead; reuse smem as the 24-channel min matrix

    {
        const int p = r * SM_RP + wg * 4;
        float4 v0 = { m[0][0] + bia0, m[0][1] + bia0, m[0][2] + bia0, m[0][3] + bia0 };
        float4 v1 = { m[1][0] + bia1, m[1][1] + bia1, m[1][2] + bia1, m[1][3] + bia1 };
        float4 v2 = { m[2][0] + bia2, m[2][1] + bia2, m[2][2] + bia2, m[2][3] + bia2 };
        float4 v3 = { m[3][0] + bia3, m[3][1] + bia3, m[3][2] + bia3, m[3][3] + bia3 };
        *(float4*)&smem[(q4 + 0) * SM_STRIDE + p] = v0;
        *(float4*)&smem[(q4 + 1) * SM_STRIDE + p] = v1;
        *(float4*)&smem[(q4 + 2) * SM_STRIDE + p] = v2;
        *(float4*)&smem[(q4 + 3) * SM_STRIDE + p] = v3;
    }
    __syncthreads();

    if (tid < 256) {                      // 4 rows x 64 cols, one pixel per thread
        const int row = tid >> 6;
        const int col = tid & 63;
        const int ho  = rt * TILE_H + row;
        if (col < WOUT && ho < HOUT) {
            float v[COUT];
            float mx = -1e30f;
            #pragma unroll
            for (int c = 0; c < COUT; ++c) {
                v[c] = smem[c * SM_STRIDE + row * SM_RP + col];
                mx = fmaxf(mx, v[c]);
            }
            float s = 0.f;
            #pragma unroll
            for (int c = 0; c < COUT; ++c) { v[c] = __expf(v[c] - mx); s += v[c]; }
            const float inv = 1.f / s;
            float* ob = out + (size_t)b * COUT * (HOUT * WOUT) + ho * WOUT + col;
            #pragma unroll
            for (int c = 0; c < COUT; ++c)
                ob[(size_t)c * (HOUT * WOUT)] = v[c] * inv;
        }
    }
}

extern "C" void kernel_launch(void* const* d_in, const int* in_sizes, int n_in,
                              void* d_out, int out_size, void* d_ws, size_t ws_size,
                              hipStream_t stream) {
    const float* x    = (const float*)d_in[0];
    const float* w    = (const float*)d_in[1];
    const float* bias = (const float*)d_in[2];
    float* out = (float*)d_out;

    conv_min_softmax_v5<<<128 * NTILES, NTHR, 0, stream>>>(x, w, bias, out);
}

// Round 4
// 498.257 us; speedup vs baseline: 2.1778x; 1.2065x over previous
//
#include <hip/hip_runtime.h>
#include <math.h>

#define CIN   3
#define DIN   16
#define HWIN  64
#define COUT  24
#define DOUT  14
#define HOUT  62
#define WOUT  62

#define TILE_H  4
#define NTILES  16                      // 62 rows -> 16 tiles of 4
#define NTHR    384                     // 6 waves; wave q owns co = 4q..4q+3
#define ROWS_IN 6                       // input rows per tile
#define RP      68                      // padded x row (floats), 16B-aligned rows
#define PLANE_F (CIN * ROWS_IN * RP)    // 1224 floats per depth plane
#define XSLAB_F (DIN * PLANE_F)         // 19584 floats: ALL 16 planes resident
#define WOFF    XSLAB_F                 // weight region base
#define WQ_F    324                     // per co-quad: [cin][kh][kd*3+kw][co4]
#define LDS_F   (XSLAB_F + 6 * WQ_F)    // 21528 fl = 86112 B (1 block/CU)
#define SM_RP     64
#define SM_STRIDE (TILE_H * SM_RP)      // 256; sm overlays the x slab after loop

// x: [128][3][16][64][64]  w: [24][3][3][3][3]  out: softmax_co(min_dz(conv+bias))
//
// v6 vs v5 (DS-pipe-bound, 73% of DS cycles = per-dz weight b128 re-reads):
//  - full 16-plane x slab staged ONCE via global_load_lds (48 dword ops/wave,
//    wave-uniform LDS base + lane*4 = the supported pattern); ONE barrier total.
//  - dz chunked 2x7: acc[7][4co][4px]; per (cin,kh) the 9 kd/kw weight float4s
//    load once into regs and each x row is read ONCE per plane (not 3x per kd),
//    feeding up to 144 FMAs. DS/wave: 162 x-pairs + 162 w-b128 (was 378+1512).
//  - DS ~130us/CU < FMA ~188us/SIMD -> FMA-bound. 1 block/CU, ~190 VGPRs.

__device__ __forceinline__ void gload_lds_dw(const float* g, float* l) {
    __builtin_amdgcn_global_load_lds(
        (const __attribute__((address_space(1))) unsigned int*)g,
        (__attribute__((address_space(3))) unsigned int*)l, 4, 0, 0);
}

__global__ __launch_bounds__(NTHR, 1) void conv_min_softmax_v6(
    const float* __restrict__ x,
    const float* __restrict__ w,
    const float* __restrict__ bias,
    float* __restrict__ out)
{
    __shared__ __align__(16) float smem[LDS_F];

    const int tid  = threadIdx.x;
    const int bid  = blockIdx.x;
    const int rt   = bid & (NTILES - 1);
    const int b    = bid >> 4;

    const int q    = __builtin_amdgcn_readfirstlane(tid >> 6);  // wave id 0..5
    const int lane = tid & 63;
    const int r    = lane >> 4;          // 0..3 output row in tile
    const int wg   = lane & 15;          // 0..15 -> wo = 4*wg..4*wg+3
    const int q4   = q * 4;

    // ---- one-time weight repack: [co][cin][kd][kh][kw] ->
    //      smem[WOFF + (co>>2)*324 + (cin*3+kh)*36 + (kd*3+kw)*4 + (co&3)]
    for (int i = tid; i < COUT * 81; i += NTHR) {
        const int co   = i / 81;
        const int rem  = i % 81;
        const int cin  = rem / 27;
        const int rem2 = rem % 27;
        const int kd   = rem2 / 9;
        const int kh   = (rem2 % 9) / 3;
        const int kw   = rem2 % 3;
        smem[WOFF + (co >> 2) * WQ_F + (cin * 3 + kh) * 36 + (kd * 3 + kw) * 4 + (co & 3)] = w[i];
    }
    const float bia0 = bias[q4 + 0], bia1 = bias[q4 + 1],
                bia2 = bias[q4 + 2], bia3 = bias[q4 + 3];

    // ---- stage ALL 16 planes: wave q stages global row rt*4+q (lane = col)
    const int grow = min(rt * TILE_H + q, HWIN - 1);
    const float* __restrict__ xrow =
        x + (size_t)b * (CIN * DIN * HWIN * HWIN) + grow * HWIN + lane;
    #pragma unroll
    for (int c = 0; c < CIN; ++c)
        #pragma unroll
        for (int p = 0; p < DIN; ++p)
            gload_lds_dw(xrow + (c * DIN + p) * (HWIN * HWIN),
                         &smem[p * PLANE_F + (c * ROWS_IN + q) * RP]);

    __syncthreads();   // drains vmcnt (global_load_lds) + lds writes; the ONLY main barrier

    float m[4][4];
    #pragma unroll
    for (int cop = 0; cop < 4; ++cop)
        #pragma unroll
        for (int i = 0; i < 4; ++i) m[cop][i] = 1e30f;

    const int vbase = r * RP + wg * 4;           // lane offset inside a pane
    const float* __restrict__ wqb = &smem[WOFF + q * WQ_F];

    #pragma unroll 1
    for (int ch = 0; ch < 2; ++ch) {             // dz = 7*ch .. 7*ch+6, planes p0..p0+8
        const int p0 = 7 * ch;

        float acc[7][4][4];
        #pragma unroll
        for (int d = 0; d < 7; ++d)
            #pragma unroll
            for (int cop = 0; cop < 4; ++cop)
                #pragma unroll
                for (int i = 0; i < 4; ++i) acc[d][cop][i] = 0.f;

        #pragma unroll 1
        for (int cin = 0; cin < CIN; ++cin) {
            #pragma unroll 1
            for (int kh = 0; kh < 3; ++kh) {
                const float* __restrict__ bp =
                    &smem[p0 * PLANE_F + cin * (ROWS_IN * RP) + kh * RP + vbase];
                const float* __restrict__ wp = wqb + (cin * 3 + kh) * 36;

                float wv[9][4];                  // [kd*3+kw][co] - loaded once
                #pragma unroll
                for (int t = 0; t < 9; ++t)
                    *(float4*)wv[t] = *(const float4*)(wp + t * 4);

                #pragma unroll
                for (int pp = 0; pp < 9; ++pp) { // sweep planes; x row read ONCE
                    const float* rp2 = bp + pp * PLANE_F;
                    const float4 a4 = *(const float4*)rp2;
                    const float2 a2 = *(const float2*)(rp2 + 4);
                    const float xr[6] = { a4.x, a4.y, a4.z, a4.w, a2.x, a2.y };
                    #pragma unroll
                    for (int kd = 0; kd < 3; ++kd) {
                        if (pp - kd < 0 || pp - kd > 6) continue;  // compile-time pruned
                        const int dzr = pp - kd;
                        #pragma unroll
                        for (int kw = 0; kw < 3; ++kw) {
                            #pragma unroll
                            for (int cop = 0; cop < 4; ++cop) {
                                const float wvv = wv[kd * 3 + kw][cop];
                                #pragma unroll
                                for (int i = 0; i < 4; ++i)
                                    acc[dzr][cop][i] = fmaf(wvv, xr[i + kw], acc[dzr][cop][i]);
                            }
                        }
                    }
                }
            }
        }

        #pragma unroll
        for (int d = 0; d < 7; ++d)
            #pragma unroll
            for (int cop = 0; cop < 4; ++cop)
                #pragma unroll
                for (int i = 0; i < 4; ++i)
                    m[cop][i] = fminf(m[cop][i], acc[d][cop][i]);
    }

    __syncthreads();      // x + weights dead; reuse smem as 24-channel min matrix

    {
        const int p = r * SM_RP + wg * 4;
        float4 v0 = { m[0][0] + bia0, m[0][1] + bia0, m[0][2] + bia0, m[0][3] + bia0 };
        float4 v1 = { m[1][0] + bia1, m[1][1] + bia1, m[1][2] + bia1, m[1][3] + bia1 };
        float4 v2 = { m[2][0] + bia2, m[2][1] + bia2, m[2][2] + bia2, m[2][3] + bia2 };
        float4 v3 = { m[3][0] + bia3, m[3][1] + bia3, m[3][2] + bia3, m[3][3] + bia3 };
        *(float4*)&smem[(q4 + 0) * SM_STRIDE + p] = v0;
        *(float4*)&smem[(q4 + 1) * SM_STRIDE + p] = v1;
        *(float4*)&smem[(q4 + 2) * SM_STRIDE + p] = v2;
        *(float4*)&smem[(q4 + 3) * SM_STRIDE + p] = v3;
    }
    __syncthreads();

    if (tid < 256) {                      // 4 rows x 64 cols, one pixel per thread
        const int row = tid >> 6;
        const int col = tid & 63;
        const int ho  = rt * TILE_H + row;
        if (col < WOUT && ho < HOUT) {
            float v[COUT];
            float mx = -1e30f;
            #pragma unroll
            for (int c = 0; c < COUT; ++c) {
                v[c] = smem[c * SM_STRIDE + row * SM_RP + col];
                mx = fmaxf(mx, v[c]);
            }
            float s = 0.f;
            #pragma unroll
            for (int c = 0; c < COUT; ++c) { v[c] = __expf(v[c] - mx); s += v[c]; }
            const float inv = 1.f / s;
            float* ob = out + (size_t)b * COUT * (HOUT * WOUT) + ho * WOUT + col;
            #pragma unroll
            for (int c = 0; c < COUT; ++c)
                ob[(size_t)c * (HOUT * WOUT)] = v[c] * inv;
        }
    }
}

extern "C" void kernel_launch(void* const* d_in, const int* in_sizes, int n_in,
                              void* d_out, int out_size, void* d_ws, size_t ws_size,
                              hipStream_t stream) {
    const float* x    = (const float*)d_in[0];
    const float* w    = (const float*)d_in[1];
    const float* bias = (const float*)d_in[2];
    float* out = (float*)d_out;

    conv_min_softmax_v6<<<128 * NTILES, NTHR, 0, stream>>>(x, w, bias, out);
}

// Round 5
// 476.835 us; speedup vs baseline: 2.2756x; 1.0449x over previous
//
#include <hip/hip_runtime.h>
#include <math.h>

#define CIN   3
#define DIN   16
#define HWIN  64
#define COUT  24
#define DOUT  14
#define HOUT  62
#define WOUT  62

#define TILE_H  4
#define NTILES  16                      // 62 rows -> 16 tiles of 4 (last 2 rows masked)
#define NTHR    512                     // 8 waves; wave q owns co = 3q..3q+2
#define ROWS_IN 6                       // input rows per tile
#define RP      68                      // padded x row (floats), 16B-aligned rows
#define PLANE_F (CIN * ROWS_IN * RP)    // 1224 floats per depth plane
#define XSLAB_F (DIN * PLANE_F)         // 19584 floats: ALL 16 planes resident
#define WOFF    XSLAB_F                 // weight region base
#define WT_F    324                     // per co-trio: [cin*3+kh][kd*3+kw][4] (slot 3 pad)
#define LDS_F   (XSLAB_F + 8 * WT_F)    // 22176 fl = 88704 B -> 1 block/CU, 8 waves
#define SM_RP     64
#define SM_STRIDE (TILE_H * SM_RP)      // 256; sm overlays the x slab after the loop

// x: [128][3][16][64][64]  w: [24][3][3][3][3]  out: softmax_co(min_dz(conv+bias))
//
// v7 vs v6 (allocator capped at 128 VGPR -> spills; 1.5 waves/SIMD -> naked DS stalls):
//  - 8 waves x 3 co each: 2 waves/SIMD everywhere (latency-hiding partner),
//    FMA/wave -25%.
//  - dz chunks 4,4,3,3 via template<int C>: acc[C][3][4] <= 48 regs, total live
//    ~115 -> no spills even at a 128-reg cap. All acc indexing compile-time.
//  - weights still amortized: 81*C FMAs per 9 broadcast-b128 weight reads.
//  DS/CU ~133us < FMA floor ~181us -> FMA-issue-bound.

__device__ __forceinline__ void gload_lds_dw(const float* g, float* l) {
    __builtin_amdgcn_global_load_lds(
        (const __attribute__((address_space(1))) unsigned int*)g,
        (__attribute__((address_space(3))) unsigned int*)l, 4, 0, 0);
}

template<int C>
__device__ __forceinline__ void do_chunk(const float* __restrict__ xv,   // smem + vbase
                                         const float* __restrict__ wqb, // smem + WOFF + q*WT_F
                                         float (&m)[3][4], const int p0)
{
    float acc[C][3][4];
    #pragma unroll
    for (int d = 0; d < C; ++d)
        #pragma unroll
        for (int cop = 0; cop < 3; ++cop)
            #pragma unroll
            for (int i = 0; i < 4; ++i) acc[d][cop][i] = 0.f;

    #pragma unroll 1
    for (int cin = 0; cin < CIN; ++cin) {
        #pragma unroll 1
        for (int kh = 0; kh < 3; ++kh) {
            const float* __restrict__ bp = xv + p0 * PLANE_F + cin * (ROWS_IN * RP) + kh * RP;
            const float* __restrict__ wp = wqb + (cin * 3 + kh) * 36;

            float4 wv[9];                        // 9 taps x 3 co (broadcast b128, .w pad)
            #pragma unroll
            for (int t = 0; t < 9; ++t) wv[t] = *(const float4*)(wp + t * 4);

            #pragma unroll
            for (int pp = 0; pp < C + 2; ++pp) { // sweep planes: x row read ONCE
                const float* rp2 = bp + pp * PLANE_F;
                const float4 a4 = *(const float4*)rp2;       // ds_read_b128
                const float2 a2 = *(const float2*)(rp2 + 4); // ds_read_b64
                const float xr[6] = { a4.x, a4.y, a4.z, a4.w, a2.x, a2.y };
                #pragma unroll
                for (int kd = 0; kd < 3; ++kd) {
                    const int d = pp - kd;
                    if (d < 0 || d >= C) continue;           // compile-time pruned
                    #pragma unroll
                    for (int kw = 0; kw < 3; ++kw) {
                        const float4 wt = wv[kd * 3 + kw];
                        const float wc[3] = { wt.x, wt.y, wt.z };
                        #pragma unroll
                        for (int cop = 0; cop < 3; ++cop)
                            #pragma unroll
                            for (int i = 0; i < 4; ++i)
                                acc[d][cop][i] = fmaf(wc[cop], xr[i + kw], acc[d][cop][i]);
                    }
                }
            }
        }
    }

    #pragma unroll
    for (int d = 0; d < C; ++d)
        #pragma unroll
        for (int cop = 0; cop < 3; ++cop)
            #pragma unroll
            for (int i = 0; i < 4; ++i)
                m[cop][i] = fminf(m[cop][i], acc[d][cop][i]);
}

__global__ __launch_bounds__(NTHR, 2) void conv_min_softmax_v7(
    const float* __restrict__ x,
    const float* __restrict__ w,
    const float* __restrict__ bias,
    float* __restrict__ out)
{
    __shared__ __align__(16) float smem[LDS_F];

    const int tid  = threadIdx.x;
    const int bid  = blockIdx.x;
    const int rt   = bid & (NTILES - 1);
    const int b    = bid >> 4;

    const int q    = __builtin_amdgcn_readfirstlane(tid >> 6);  // wave id 0..7 (uniform)
    const int lane = tid & 63;
    const int r    = lane >> 4;          // 0..3 output row in tile
    const int wg   = lane & 15;          // 0..15 -> wo = 4*wg..4*wg+3
    const int q3   = q * 3;

    // ---- one-time weight repack: [co][cin][kd][kh][kw] ->
    //      smem[WOFF + (co/3)*WT_F + (cin*3+kh)*36 + (kd*3+kw)*4 + (co%3)]
    for (int i = tid; i < COUT * 81; i += NTHR) {
        const int co   = i / 81;
        const int rem  = i % 81;
        const int cin  = rem / 27;
        const int rem2 = rem % 27;
        const int kd   = rem2 / 9;
        const int kh   = (rem2 % 9) / 3;
        const int kw   = rem2 % 3;
        smem[WOFF + (co / 3) * WT_F + (cin * 3 + kh) * 36 + (kd * 3 + kw) * 4 + (co % 3)] = w[i];
    }
    const float bia[3] = { bias[q3 + 0], bias[q3 + 1], bias[q3 + 2] };

    // ---- stage ALL 16 planes via global_load_lds: 288 rows, 36 per wave.
    //      row index j = q*36 + k: p = 2q + k/18, sub = k%18 (exact since 36 = 2*18)
    {
        const float* __restrict__ xb =
            x + (size_t)b * (CIN * DIN * HWIN * HWIN) + lane;
        #pragma unroll
        for (int k = 0; k < 36; ++k) {
            const int p    = 2 * q + (k >= 18 ? 1 : 0);
            const int sub  = k % 18;
            const int cin  = sub / 6;
            const int row  = sub % 6;
            const int grow = min(rt * TILE_H + row, HWIN - 1);   // clamp last tile
            gload_lds_dw(xb + ((cin * DIN + p) * (HWIN * HWIN) + grow * HWIN),
                         &smem[p * PLANE_F + (cin * ROWS_IN + row) * RP]);
        }
    }
    __syncthreads();   // drains global_load_lds + weight repack; ONLY main barrier

    float m[3][4];
    #pragma unroll
    for (int cop = 0; cop < 3; ++cop)
        #pragma unroll
        for (int i = 0; i < 4; ++i) m[cop][i] = 1e30f;

    const float* __restrict__ xv  = &smem[r * RP + wg * 4];
    const float* __restrict__ wqb = &smem[WOFF + q * WT_F];

    // dz chunks: [0,4) [4,8) [8,11) [11,14)
    do_chunk<4>(xv, wqb, m, 0);
    do_chunk<4>(xv, wqb, m, 4);
    do_chunk<3>(xv, wqb, m, 8);
    do_chunk<3>(xv, wqb, m, 11);

    __syncthreads();      // x + weights dead; reuse smem as 24-channel min matrix

    {
        const int p = r * SM_RP + wg * 4;
        #pragma unroll
        for (int cop = 0; cop < 3; ++cop) {
            float4 v = { m[cop][0] + bia[cop], m[cop][1] + bia[cop],
                         m[cop][2] + bia[cop], m[cop][3] + bia[cop] };
            *(float4*)&smem[(q3 + cop) * SM_STRIDE + p] = v;
        }
    }
    __syncthreads();

    if (tid < 256) {                      // 4 rows x 64 cols, one pixel per thread
        const int row = tid >> 6;
        const int col = tid & 63;
        const int ho  = rt * TILE_H + row;
        if (col < WOUT && ho < HOUT) {
            float v[COUT];
            float mx = -1e30f;
            #pragma unroll
            for (int c = 0; c < COUT; ++c) {
                v[c] = smem[c * SM_STRIDE + row * SM_RP + col];
                mx = fmaxf(mx, v[c]);
            }
            float s = 0.f;
            #pragma unroll
            for (int c = 0; c < COUT; ++c) { v[c] = __expf(v[c] - mx); s += v[c]; }
            const float inv = 1.f / s;
            float* ob = out + (size_t)b * COUT * (HOUT * WOUT) + ho * WOUT + col;
            #pragma unroll
            for (int c = 0; c < COUT; ++c)
                ob[(size_t)c * (HOUT * WOUT)] = v[c] * inv;
        }
    }
}

extern "C" void kernel_launch(void* const* d_in, const int* in_sizes, int n_in,
                              void* d_out, int out_size, void* d_ws, size_t ws_size,
                              hipStream_t stream) {
    const float* x    = (const float*)d_in[0];
    const float* w    = (const float*)d_in[1];
    const float* bias = (const float*)d_in[2];
    float* out = (float*)d_out;

    conv_min_softmax_v7<<<128 * NTILES, NTHR, 0, stream>>>(x, w, bias, out);
}